// Round 4
// baseline (143.681 us; speedup 1.0000x reference)
//
#include <hip/hip_runtime.h>
#include <hip/hip_bf16.h>
#include <cstdint>
#include <cstddef>

#define BB   64
#define CINN 64
#define TS   4096
#define FF   128
#define KS   64
#define TOUT (TS - KS + 1)   // 4033

// ---- fused-kernel tiling ----
#define TSEG 256             // outputs per block (one 256-output banded-MFMA tile, 16x16 D)
#define XROW 320             // t-extent of staged x / computed y (TSEG + KS)
#define SXW  324             // xT row stride in u32 words (mult of 4 -> b128 rows, 2-way banks)
#define YWW  168             // yL row stride in u32 words (336 bf16: 320 y + 16 zero pad)
#define GF   32              // filters per group (4 sequential groups -> yL fits 21.5 KB)

typedef __attribute__((ext_vector_type(8))) short short8;
typedef __attribute__((ext_vector_type(4))) float f32x4;
union FragU { unsigned int u[4]; short8 v; uint4 q4; };

static __device__ __forceinline__ unsigned int f2bf_u(float f) {
    __hip_bfloat16 h = __float2bfloat16(f);
    return (unsigned int)*reinterpret_cast<unsigned short*>(&h);
}

// ---- Setup: banded temporal-B fragments (R5/R6-validated) + sw bf16 fragments +
//      fused norm weights ----
// bandB[(f*3+s)*64 + lane] = 8 bf16: B_s[k=8q+j][n] = cw[32s+k-n] (0 outside [0,64))
// swF[(ft*2+s)*64 + lane]  = 8 bf16: sw[16ft+(l&15)][32s+8q+j]  (B-operand frag, N=filter)
__global__ void k_band(const float* __restrict__ cw, const float* __restrict__ sw,
                       const float* __restrict__ weight,
                       uint4* __restrict__ bandB, float* __restrict__ wnf,
                       uint4* __restrict__ swF) {
    const int f = blockIdx.x, l = threadIdx.x;
    const int n = l & 15, q = l >> 4;
    for (int s = 0; s < 3; ++s) {
        FragU o;
#pragma unroll
        for (int i = 0; i < 4; ++i) {
            int i0 = 32 * s + 8 * q + 2 * i - n;
            int i1 = i0 + 1;
            float a = (i0 >= 0 && i0 < KS) ? cw[(size_t)f * KS + i0] : 0.f;
            float c = (i1 >= 0 && i1 < KS) ? cw[(size_t)f * KS + i1] : 0.f;
            o.u[i] = f2bf_u(a) | (f2bf_u(c) << 16);
        }
        bandB[((size_t)f * 3 + s) * 64 + l] = o.q4;
    }
    // sw bf16 fragments: blocks f = 0,16,32,... build filter-tile ft = f>>4
    if ((f & 15) == 0) {
        const int ft = f >> 4;
        for (int s = 0; s < 2; ++s) {
            FragU o;
#pragma unroll
            for (int i = 0; i < 4; ++i) {
                const float* sr = sw + (size_t)(16 * ft + n) * CINN + 32 * s + 8 * q + 2 * i;
                o.u[i] = f2bf_u(sr[0]) | (f2bf_u(sr[1]) << 16);
            }
            swF[((size_t)ft * 2 + s) * 64 + l] = o.q4;
        }
    }
    // per-filter weight * rsqrt(|sw_f|^2 * |cw_f|^2) * scale / TOUT
    float a = sw[(size_t)f * CINN + l], c = cw[(size_t)f * KS + l];
    float v = a * a, u = c * c;
    for (int off = 32; off > 0; off >>= 1) {
        v += __shfl_down(v, off, 64);
        u += __shfl_down(u, off, 64);
    }
    if (l == 0) wnf[f] = weight[f] * rsqrtf(v * u) * (64.0f / (float)TOUT);
}

// ============ Fused kernel, 65.6 KB LDS -> 2 blocks/CU (32 waves, full TLP) ============
// One 256-output tile per block; filters processed in 4 sequential groups of 32 so the
// yL transpose buffer is 21.5 KB. sw fragments read straight from L2 (16 KB, hot).
// xT layout [ch-pair][t], b128 staging writes (bank-uniform, R3-validated).
// Spatial GEMM: swapped operands mfma(x_frag, sw_frag) -> D[t][filter], lane-local
// bf16 pack, ds_write_b64, zero shuffles (R2/R3-validated numerics).
__global__ __launch_bounds__(1024, 8) void k_fused(
    const float* __restrict__ x, const uint4* __restrict__ swF,
    const uint4* __restrict__ bandB, const float* __restrict__ wnf,
    const float* __restrict__ bias, float* __restrict__ out)
{
    __shared__ unsigned int xT[32 * SXW];   // 41,472 B
    __shared__ unsigned int yL[GF * YWW];   // 21,504 B (first 20,480 B reused as sq partials)
    __shared__ float sqA[XROW];             // 1,280 B
    __shared__ float rinvA[XROW];           // 1,280 B
    __shared__ float wred[16];

    const int tid = threadIdx.x;
    const int w = tid >> 6, l = tid & 63;
    const int m = l & 15, q = l >> 4;
    const int b = blockIdx.y;
    const int t0 = blockIdx.x * TSEG;

    // ---------- Phase 1: stage xT (bf16 ch-pairs, [cp][t]) + per-wave sq partials ----------
    {
        const float* xb = x + (size_t)b * CINN * TS;
        float* sqp = (float*)yL;            // [16][XROW] f32 partials
        float4 s4a = {0.f, 0.f, 0.f, 0.f}, s4b = {0.f, 0.f, 0.f, 0.f};
#pragma unroll
        for (int r = 0; r < 2; ++r) {
            const int cp = w + 16 * r;      // channel pair (2cp, 2cp+1)
            const float* x0 = xb + (size_t)(2 * cp) * TS;
            {
                int p = t0 + 4 * l; if (p > TS - 4) p = TS - 4;   // tail clamp (finite dups)
                float4 v0 = *(const float4*)(x0 + p);
                float4 v1 = *(const float4*)(x0 + TS + p);
                s4a.x += v0.x * v0.x + v1.x * v1.x;
                s4a.y += v0.y * v0.y + v1.y * v1.y;
                s4a.z += v0.z * v0.z + v1.z * v1.z;
                s4a.w += v0.w * v0.w + v1.w * v1.w;
                FragU o;
                o.u[0] = f2bf_u(v0.x) | (f2bf_u(v1.x) << 16);
                o.u[1] = f2bf_u(v0.y) | (f2bf_u(v1.y) << 16);
                o.u[2] = f2bf_u(v0.z) | (f2bf_u(v1.z) << 16);
                o.u[3] = f2bf_u(v0.w) | (f2bf_u(v1.w) << 16);
                *(uint4*)&xT[cp * SXW + 4 * l] = o.q4;            // aligned b128, uniform banks
            }
            if (l < 16) {                   // tail t-local 256..319
                int p = t0 + 256 + 4 * l; if (p > TS - 4) p = TS - 4;
                float4 v0 = *(const float4*)(x0 + p);
                float4 v1 = *(const float4*)(x0 + TS + p);
                s4b.x += v0.x * v0.x + v1.x * v1.x;
                s4b.y += v0.y * v0.y + v1.y * v1.y;
                s4b.z += v0.z * v0.z + v1.z * v1.z;
                s4b.w += v0.w * v0.w + v1.w * v1.w;
                FragU o;
                o.u[0] = f2bf_u(v0.x) | (f2bf_u(v1.x) << 16);
                o.u[1] = f2bf_u(v0.y) | (f2bf_u(v1.y) << 16);
                o.u[2] = f2bf_u(v0.z) | (f2bf_u(v1.z) << 16);
                o.u[3] = f2bf_u(v0.w) | (f2bf_u(v1.w) << 16);
                *(uint4*)&xT[cp * SXW + 256 + 4 * l] = o.q4;
            }
        }
        *(float4*)(sqp + w * XROW + 4 * l) = s4a;
        if (l < 16) *(float4*)(sqp + w * XROW + 256 + 4 * l) = s4b;
    }
    __syncthreads();

    // ---------- Phase 2: reduce sq partials into sqA ----------
    if (tid < XROW) {
        const float* sqp = (const float*)yL;
        float s = 0.f;
#pragma unroll
        for (int i = 0; i < 16; ++i) s += sqp[i * XROW + tid];
        sqA[tid] = s;
    }
    __syncthreads();

    // ---------- Phase 3a (wave 15): sliding-window rinv: sqA -> rinvA ----------
    // Runs concurrently with group-0 GEMM; both complete before the group-0 sync.
    if (w == 15 && l < 32) {
        const int base = 8 * l;
        float s = 0.f, hd[8], tl[8];
#pragma unroll
        for (int k = 0; k < 64; ++k) {
            float v = sqA[base + k];
            if (k < 8) hd[k] = v;
            s += v;
        }
#pragma unroll
        for (int j = 0; j < 8; ++j) tl[j] = sqA[base + 64 + j];
#pragma unroll
        for (int j = 0; j < 8; ++j) {
            int tpos = t0 + base + j;
            rinvA[base + j] = (tpos < TOUT) ? rsqrtf(s) : 0.f;   // masks tail outputs
            s += tl[j] - hd[j];
        }
    }

    // ---------- main loop: 4 filter-groups of 32 ----------
    float acc = 0.f;
    for (int g = 0; g < 4; ++g) {
        // ---- GEMM (swapped operands): filter-tiles 2g, 2g+1 -> yL rows 0..31 ----
        {
            const int quad = w & 1;
            const int ft = 2 * g + quad;
            for (int tt = (w >> 1); tt < 20; tt += 8) {
                FragU b0, b1;               // x frags: strided b32 reads (2-way banks)
#pragma unroll
                for (int i = 0; i < 4; ++i) {
                    b0.u[i] = xT[(4 * q + i) * SXW + 16 * tt + m];
                    b1.u[i] = xT[(16 + 4 * q + i) * SXW + 16 * tt + m];
                }
                FragU s0, s1;               // transient sw frags straight from L2
                s0.q4 = swF[((size_t)ft * 2 + 0) * 64 + l];
                s1.q4 = swF[((size_t)ft * 2 + 1) * 64 + l];
                f32x4 d = {0.f, 0.f, 0.f, 0.f};
                d = __builtin_amdgcn_mfma_f32_16x16x32_bf16(b0.v, s0.v, d, 0, 0, 0);
                d = __builtin_amdgcn_mfma_f32_16x16x32_bf16(b1.v, s1.v, d, 0, 0, 0);
                const int fl = 16 * quad + m;                // group-local filter row
                uint2 o;
                o.x = f2bf_u(d[0]) | (f2bf_u(d[1]) << 16);   // t = 16tt+4q, +1
                o.y = f2bf_u(d[2]) | (f2bf_u(d[3]) << 16);   // t = 16tt+4q+2, +3
                *(uint2*)(yL + fl * YWW + 8 * tt + 2 * q) = o;
            }
            // zero finite-pad words 160..167 of each row once; GEMM never writes >=160,
            // so the pads stay zero for all later groups.
            if (g == 0 && tid < 256) yL[(tid >> 3) * YWW + 160 + (tid & 7)] = 0u;
        }
        __syncthreads();

        // ---- banded temporal MFMA: wave w consumes group-local filters 2w, 2w+1 ----
        {
            float rr[4];
#pragma unroll
            for (int r = 0; r < 4; ++r) rr[r] = rinvA[64 * q + 16 * r + m];   // broadcast reads
#pragma unroll
            for (int j = 0; j < 2; ++j) {
                const int fl = 2 * w + j;                    // 0..31
                const int f  = GF * g + fl;
                const uint4* bb = bandB + (size_t)f * 3 * 64;
                FragU B0, B1, B2;
                B0.q4 = bb[l]; B1.q4 = bb[64 + l]; B2.q4 = bb[128 + l];
                const int abase = fl * YWW + 8 * m + 4 * q;  // 16B-aligned word index
                FragU a0, a1, a2;
                a0.q4 = *(const uint4*)(yL + abase);
                a1.q4 = *(const uint4*)(yL + abase + 16);
                a2.q4 = *(const uint4*)(yL + abase + 32);
                f32x4 d = {0.f, 0.f, 0.f, 0.f};
                d = __builtin_amdgcn_mfma_f32_16x16x32_bf16(a0.v, B0.v, d, 0, 0, 0);
                d = __builtin_amdgcn_mfma_f32_16x16x32_bf16(a1.v, B1.v, d, 0, 0, 0);
                d = __builtin_amdgcn_mfma_f32_16x16x32_bf16(a2.v, B2.v, d, 0, 0, 0);
                float facc = 0.f;
#pragma unroll
                for (int r = 0; r < 4; ++r) facc += fabsf(d[r]) * rr[r];
                acc += wnf[f] * facc;
            }
        }
        __syncthreads();                    // yL reusable for next group's GEMM
    }

    // ---------- block reduction + atomic ----------
    for (int off = 32; off > 0; off >>= 1) acc += __shfl_down(acc, off, 64);
    if (l == 0) wred[w] = acc;
    __syncthreads();
    if (tid == 0) {
        float s = 0.f;
#pragma unroll
        for (int i = 0; i < 16; ++i) s += wred[i];
        atomicAdd(out + b, s);
    }
    if (blockIdx.x == 0 && tid < FF) {
        float v = bias[tid];
        for (int off = 32; off > 0; off >>= 1) v += __shfl_down(v, off, 64);
        if ((tid & 63) == 0) atomicAdd(out + b, v);
    }
}

// --------- Fallback (no workspace): one block per (f,b), LDS rows ----------
__global__ __launch_bounds__(256) void k_naive(
    const float* __restrict__ x, const float* __restrict__ cw,
    const float* __restrict__ sw, const float* __restrict__ weight,
    const float* __restrict__ bias, float* __restrict__ out)
{
    __shared__ float yl[TS];
    __shared__ float ql[TS];
    __shared__ float wred[4];
    const int f = blockIdx.x, b = blockIdx.y, tid = threadIdx.x;
    for (int t = tid; t < TS; t += 256) {
        float a = 0.f, s = 0.f;
        for (int c = 0; c < CINN; ++c) {
            float v = x[((size_t)b * CINN + c) * TS + t];
            a += sw[(size_t)f * CINN + c] * v;
            s += v * v;
        }
        yl[t] = a; ql[t] = s;
    }
    __syncthreads();
    float acc = 0.f;
    for (int t = tid; t < TOUT; t += 256) {
        float cv = 0.f, sl = 0.f;
        for (int k = 0; k < KS; ++k) { cv += cw[(size_t)f * KS + k] * yl[t + k]; sl += ql[t + k]; }
        acc += fabsf(cv) * rsqrtf(sl);
    }
    float ssw = 0.f, scw = 0.f;
    for (int c = 0; c < CINN; ++c) { float v = sw[(size_t)f * CINN + c]; ssw += v * v; }
    for (int k = 0; k < KS; ++k)   { float v = cw[(size_t)f * KS + k];  scw += v * v; }
    const float wnf = weight[f] * rsqrtf(ssw * scw) * 64.0f / (float)TOUT;
    for (int off = 32; off > 0; off >>= 1) acc += __shfl_down(acc, off, 64);
    if ((tid & 63) == 0) wred[tid >> 6] = acc;
    __syncthreads();
    if (tid == 0) {
        float tot = (wred[0] + wred[1] + wred[2] + wred[3]) * wnf;
        if (f == 0) {
            float bsum = 0.f;
            for (int ff = 0; ff < FF; ++ff) bsum += bias[ff];
            tot += bsum;
        }
        atomicAdd(out + b, tot);
    }
}

extern "C" void kernel_launch(void* const* d_in, const int* in_sizes, int n_in,
                              void* d_out, int out_size, void* d_ws, size_t ws_size,
                              hipStream_t stream) {
    const float* x  = (const float*)d_in[0];
    const float* cw = (const float*)d_in[1];   // [F,K]
    const float* sw = (const float*)d_in[2];   // [F,CIN]
    const float* w  = (const float*)d_in[3];   // [F]
    const float* bs = (const float*)d_in[4];   // [F]
    float* out = (float*)d_out;

    hipMemsetAsync(d_out, 0, (size_t)out_size * sizeof(float), stream);

    const size_t bandBytes = (size_t)FF * 3 * 64 * 16;        // 384 KB
    const size_t wnBytes   = (size_t)FF * sizeof(float);
    const size_t swfBytes  = (size_t)(FF / 16) * 2 * 64 * 16; // 16 KB

    if (bandBytes + wnBytes + swfBytes <= ws_size) {
        uint4* bandB = (uint4*)d_ws;
        float* wnf   = (float*)((char*)d_ws + bandBytes);
        uint4* swF   = (uint4*)((char*)d_ws + bandBytes + wnBytes);
        k_band <<<dim3(FF), 64, 0, stream>>>(cw, sw, w, bandB, wnf, swF);
        k_fused<<<dim3(TS / TSEG, BB), 1024, 0, stream>>>(x, swF, bandB, wnf, bs, out);
    } else {
        k_naive<<<dim3(FF, BB), 256, 0, stream>>>(x, cw, sw, w, bs, out);
    }
}

// Round 5
// 140.077 us; speedup vs baseline: 1.0257x; 1.0257x over previous
//
#include <hip/hip_runtime.h>
#include <hip/hip_bf16.h>
#include <cstdint>
#include <cstddef>

#define BB   64
#define CINN 64
#define TS   4096
#define FF   128
#define KS   64
#define TOUT (TS - KS + 1)   // 4033

// ---- fused-kernel tiling ----
#define TSEG 256             // outputs per block (one 256-output banded-MFMA tile, 16x16 D)
#define XROW 320             // t-extent of staged x / computed y (TSEG + KS)
#define SXW  324             // xT row stride in u32 words (mult of 4 -> b128 rows, 2-way banks)
#define YWW  168             // yL row stride in u32 words (336 bf16: 320 y + 16 zero pad)
#define GF   32              // filters per group (4 sequential groups -> yL fits 21.5 KB)

typedef __attribute__((ext_vector_type(8))) short short8;
typedef __attribute__((ext_vector_type(4))) float f32x4;
union FragU { unsigned int u[4]; short8 v; uint4 q4; };

static __device__ __forceinline__ unsigned int f2bf_u(float f) {
    __hip_bfloat16 h = __float2bfloat16(f);
    return (unsigned int)*reinterpret_cast<unsigned short*>(&h);
}

// ---- Setup: banded temporal-B fragments (R5/R6-validated) + sw bf16 fragments +
//      fused norm weights ----
// bandB[(f*3+s)*64 + lane] = 8 bf16: B_s[k=8q+j][n] = cw[32s+k-n] (0 outside [0,64))
// swF[(ft*2+s)*64 + lane]  = 8 bf16: sw[16ft+(l&15)][32s+8q+j]  (B-operand frag, N=filter)
__global__ void k_band(const float* __restrict__ cw, const float* __restrict__ sw,
                       const float* __restrict__ weight,
                       uint4* __restrict__ bandB, float* __restrict__ wnf,
                       uint4* __restrict__ swF) {
    const int f = blockIdx.x, l = threadIdx.x;
    const int n = l & 15, q = l >> 4;
    for (int s = 0; s < 3; ++s) {
        FragU o;
#pragma unroll
        for (int i = 0; i < 4; ++i) {
            int i0 = 32 * s + 8 * q + 2 * i - n;
            int i1 = i0 + 1;
            float a = (i0 >= 0 && i0 < KS) ? cw[(size_t)f * KS + i0] : 0.f;
            float c = (i1 >= 0 && i1 < KS) ? cw[(size_t)f * KS + i1] : 0.f;
            o.u[i] = f2bf_u(a) | (f2bf_u(c) << 16);
        }
        bandB[((size_t)f * 3 + s) * 64 + l] = o.q4;
    }
    // sw bf16 fragments: blocks f = 0,16,32,... build filter-tile ft = f>>4
    if ((f & 15) == 0) {
        const int ft = f >> 4;
        for (int s = 0; s < 2; ++s) {
            FragU o;
#pragma unroll
            for (int i = 0; i < 4; ++i) {
                const float* sr = sw + (size_t)(16 * ft + n) * CINN + 32 * s + 8 * q + 2 * i;
                o.u[i] = f2bf_u(sr[0]) | (f2bf_u(sr[1]) << 16);
            }
            swF[((size_t)ft * 2 + s) * 64 + l] = o.q4;
        }
    }
    // per-filter weight * rsqrt(|sw_f|^2 * |cw_f|^2) * scale / TOUT
    float a = sw[(size_t)f * CINN + l], c = cw[(size_t)f * KS + l];
    float v = a * a, u = c * c;
    for (int off = 32; off > 0; off >>= 1) {
        v += __shfl_down(v, off, 64);
        u += __shfl_down(u, off, 64);
    }
    if (l == 0) wnf[f] = weight[f] * rsqrtf(v * u) * (64.0f / (float)TOUT);
}

// ============ Fused kernel, 65.6 KB LDS -> 2 blocks/CU via NATURAL limits ============
// R4 post-mortem: __launch_bounds__(1024,8) coerced the allocator to 32 VGPRs and it
// spilled ~260 B/thread (WRITE_SIZE 68 MB). R3 proved this code shape fits in 52 VGPRs
// under (1024,4); 52 <= 64 means 8 waves/SIMD (2 blocks/CU) fit WITHOUT the bound.
// LDS 66 KB is then the binding (and intended) occupancy limit.
// One 256-output tile per block; filters in 4 sequential groups of 32 (yL = 21.5 KB).
// xT layout [ch-pair][t], b128 staging writes (bank-uniform, R3-validated).
// Spatial GEMM: swapped operands mfma(x_frag, sw_frag) -> D[t][filter], lane-local
// bf16 pack, ds_write_b64, zero shuffles (R2/R3-validated numerics).
__global__ __launch_bounds__(1024, 4) void k_fused(
    const float* __restrict__ x, const uint4* __restrict__ swF,
    const uint4* __restrict__ bandB, const float* __restrict__ wnf,
    const float* __restrict__ bias, float* __restrict__ out)
{
    __shared__ unsigned int xT[32 * SXW];   // 41,472 B
    __shared__ unsigned int yL[GF * YWW];   // 21,504 B (first 20,480 B reused as sq partials)
    __shared__ float sqA[XROW];             // 1,280 B
    __shared__ float rinvA[XROW];           // 1,280 B
    __shared__ float wred[16];

    const int tid = threadIdx.x;
    const int w = tid >> 6, l = tid & 63;
    const int m = l & 15, q = l >> 4;
    const int b = blockIdx.y;
    const int t0 = blockIdx.x * TSEG;

    // ---------- Phase 1: stage xT (bf16 ch-pairs, [cp][t]) + per-wave sq partials ----------
    {
        const float* xb = x + (size_t)b * CINN * TS;
        float* sqp = (float*)yL;            // [16][XROW] f32 partials
        float4 s4a = {0.f, 0.f, 0.f, 0.f}, s4b = {0.f, 0.f, 0.f, 0.f};
#pragma unroll
        for (int r = 0; r < 2; ++r) {
            const int cp = w + 16 * r;      // channel pair (2cp, 2cp+1)
            const float* x0 = xb + (size_t)(2 * cp) * TS;
            {
                int p = t0 + 4 * l; if (p > TS - 4) p = TS - 4;   // tail clamp (finite dups)
                float4 v0 = *(const float4*)(x0 + p);
                float4 v1 = *(const float4*)(x0 + TS + p);
                s4a.x += v0.x * v0.x + v1.x * v1.x;
                s4a.y += v0.y * v0.y + v1.y * v1.y;
                s4a.z += v0.z * v0.z + v1.z * v1.z;
                s4a.w += v0.w * v0.w + v1.w * v1.w;
                FragU o;
                o.u[0] = f2bf_u(v0.x) | (f2bf_u(v1.x) << 16);
                o.u[1] = f2bf_u(v0.y) | (f2bf_u(v1.y) << 16);
                o.u[2] = f2bf_u(v0.z) | (f2bf_u(v1.z) << 16);
                o.u[3] = f2bf_u(v0.w) | (f2bf_u(v1.w) << 16);
                *(uint4*)&xT[cp * SXW + 4 * l] = o.q4;            // aligned b128, uniform banks
            }
            if (l < 16) {                   // tail t-local 256..319
                int p = t0 + 256 + 4 * l; if (p > TS - 4) p = TS - 4;
                float4 v0 = *(const float4*)(x0 + p);
                float4 v1 = *(const float4*)(x0 + TS + p);
                s4b.x += v0.x * v0.x + v1.x * v1.x;
                s4b.y += v0.y * v0.y + v1.y * v1.y;
                s4b.z += v0.z * v0.z + v1.z * v1.z;
                s4b.w += v0.w * v0.w + v1.w * v1.w;
                FragU o;
                o.u[0] = f2bf_u(v0.x) | (f2bf_u(v1.x) << 16);
                o.u[1] = f2bf_u(v0.y) | (f2bf_u(v1.y) << 16);
                o.u[2] = f2bf_u(v0.z) | (f2bf_u(v1.z) << 16);
                o.u[3] = f2bf_u(v0.w) | (f2bf_u(v1.w) << 16);
                *(uint4*)&xT[cp * SXW + 256 + 4 * l] = o.q4;
            }
        }
        *(float4*)(sqp + w * XROW + 4 * l) = s4a;
        if (l < 16) *(float4*)(sqp + w * XROW + 256 + 4 * l) = s4b;
    }
    __syncthreads();

    // ---------- Phase 2: reduce sq partials into sqA ----------
    if (tid < XROW) {
        const float* sqp = (const float*)yL;
        float s = 0.f;
#pragma unroll
        for (int i = 0; i < 16; ++i) s += sqp[i * XROW + tid];
        sqA[tid] = s;
    }
    __syncthreads();

    // ---------- Phase 3a (wave 15): sliding-window rinv: sqA -> rinvA ----------
    // Runs concurrently with group-0 GEMM; both complete before the group-0 sync.
    if (w == 15 && l < 32) {
        const int base = 8 * l;
        float s = 0.f, hd[8], tl[8];
#pragma unroll
        for (int k = 0; k < 64; ++k) {
            float v = sqA[base + k];
            if (k < 8) hd[k] = v;
            s += v;
        }
#pragma unroll
        for (int j = 0; j < 8; ++j) tl[j] = sqA[base + 64 + j];
#pragma unroll
        for (int j = 0; j < 8; ++j) {
            int tpos = t0 + base + j;
            rinvA[base + j] = (tpos < TOUT) ? rsqrtf(s) : 0.f;   // masks tail outputs
            s += tl[j] - hd[j];
        }
    }

    // ---------- main loop: 4 filter-groups of 32 ----------
    float acc = 0.f;
    for (int g = 0; g < 4; ++g) {
        // ---- GEMM (swapped operands): filter-tiles 2g, 2g+1 -> yL rows 0..31 ----
        {
            const int quad = w & 1;
            const int ft = 2 * g + quad;
            for (int tt = (w >> 1); tt < 20; tt += 8) {
                FragU b0, b1;               // x frags: strided b32 reads (2-way banks)
#pragma unroll
                for (int i = 0; i < 4; ++i) {
                    b0.u[i] = xT[(4 * q + i) * SXW + 16 * tt + m];
                    b1.u[i] = xT[(16 + 4 * q + i) * SXW + 16 * tt + m];
                }
                FragU s0, s1;               // transient sw frags straight from L2
                s0.q4 = swF[((size_t)ft * 2 + 0) * 64 + l];
                s1.q4 = swF[((size_t)ft * 2 + 1) * 64 + l];
                f32x4 d = {0.f, 0.f, 0.f, 0.f};
                d = __builtin_amdgcn_mfma_f32_16x16x32_bf16(b0.v, s0.v, d, 0, 0, 0);
                d = __builtin_amdgcn_mfma_f32_16x16x32_bf16(b1.v, s1.v, d, 0, 0, 0);
                const int fl = 16 * quad + m;                // group-local filter row
                uint2 o;
                o.x = f2bf_u(d[0]) | (f2bf_u(d[1]) << 16);   // t = 16tt+4q, +1
                o.y = f2bf_u(d[2]) | (f2bf_u(d[3]) << 16);   // t = 16tt+4q+2, +3
                *(uint2*)(yL + fl * YWW + 8 * tt + 2 * q) = o;
            }
            // zero finite-pad words 160..167 of each row once; GEMM never writes >=160,
            // so the pads stay zero for all later groups.
            if (g == 0 && tid < 256) yL[(tid >> 3) * YWW + 160 + (tid & 7)] = 0u;
        }
        __syncthreads();

        // ---- banded temporal MFMA: wave w consumes group-local filters 2w, 2w+1 ----
        {
            float rr[4];
#pragma unroll
            for (int r = 0; r < 4; ++r) rr[r] = rinvA[64 * q + 16 * r + m];   // broadcast reads
#pragma unroll
            for (int j = 0; j < 2; ++j) {
                const int fl = 2 * w + j;                    // 0..31
                const int f  = GF * g + fl;
                const uint4* bb = bandB + (size_t)f * 3 * 64;
                FragU B0, B1, B2;
                B0.q4 = bb[l]; B1.q4 = bb[64 + l]; B2.q4 = bb[128 + l];
                const int abase = fl * YWW + 8 * m + 4 * q;  // 16B-aligned word index
                FragU a0, a1, a2;
                a0.q4 = *(const uint4*)(yL + abase);
                a1.q4 = *(const uint4*)(yL + abase + 16);
                a2.q4 = *(const uint4*)(yL + abase + 32);
                f32x4 d = {0.f, 0.f, 0.f, 0.f};
                d = __builtin_amdgcn_mfma_f32_16x16x32_bf16(a0.v, B0.v, d, 0, 0, 0);
                d = __builtin_amdgcn_mfma_f32_16x16x32_bf16(a1.v, B1.v, d, 0, 0, 0);
                d = __builtin_amdgcn_mfma_f32_16x16x32_bf16(a2.v, B2.v, d, 0, 0, 0);
                float facc = 0.f;
#pragma unroll
                for (int r = 0; r < 4; ++r) facc += fabsf(d[r]) * rr[r];
                acc += wnf[f] * facc;
            }
        }
        __syncthreads();                    // yL reusable for next group's GEMM
    }

    // ---------- block reduction + atomic ----------
    for (int off = 32; off > 0; off >>= 1) acc += __shfl_down(acc, off, 64);
    if (l == 0) wred[w] = acc;
    __syncthreads();
    if (tid == 0) {
        float s = 0.f;
#pragma unroll
        for (int i = 0; i < 16; ++i) s += wred[i];
        atomicAdd(out + b, s);
    }
    if (blockIdx.x == 0 && tid < FF) {
        float v = bias[tid];
        for (int off = 32; off > 0; off >>= 1) v += __shfl_down(v, off, 64);
        if ((tid & 63) == 0) atomicAdd(out + b, v);
    }
}

// --------- Fallback (no workspace): one block per (f,b), LDS rows ----------
__global__ __launch_bounds__(256) void k_naive(
    const float* __restrict__ x, const float* __restrict__ cw,
    const float* __restrict__ sw, const float* __restrict__ weight,
    const float* __restrict__ bias, float* __restrict__ out)
{
    __shared__ float yl[TS];
    __shared__ float ql[TS];
    __shared__ float wred[4];
    const int f = blockIdx.x, b = blockIdx.y, tid = threadIdx.x;
    for (int t = tid; t < TS; t += 256) {
        float a = 0.f, s = 0.f;
        for (int c = 0; c < CINN; ++c) {
            float v = x[((size_t)b * CINN + c) * TS + t];
            a += sw[(size_t)f * CINN + c] * v;
            s += v * v;
        }
        yl[t] = a; ql[t] = s;
    }
    __syncthreads();
    float acc = 0.f;
    for (int t = tid; t < TOUT; t += 256) {
        float cv = 0.f, sl = 0.f;
        for (int k = 0; k < KS; ++k) { cv += cw[(size_t)f * KS + k] * yl[t + k]; sl += ql[t + k]; }
        acc += fabsf(cv) * rsqrtf(sl);
    }
    float ssw = 0.f, scw = 0.f;
    for (int c = 0; c < CINN; ++c) { float v = sw[(size_t)f * CINN + c]; ssw += v * v; }
    for (int k = 0; k < KS; ++k)   { float v = cw[(size_t)f * KS + k];  scw += v * v; }
    const float wnf = weight[f] * rsqrtf(ssw * scw) * 64.0f / (float)TOUT;
    for (int off = 32; off > 0; off >>= 1) acc += __shfl_down(acc, off, 64);
    if ((tid & 63) == 0) wred[tid >> 6] = acc;
    __syncthreads();
    if (tid == 0) {
        float tot = (wred[0] + wred[1] + wred[2] + wred[3]) * wnf;
        if (f == 0) {
            float bsum = 0.f;
            for (int ff = 0; ff < FF; ++ff) bsum += bias[ff];
            tot += bsum;
        }
        atomicAdd(out + b, tot);
    }
}

extern "C" void kernel_launch(void* const* d_in, const int* in_sizes, int n_in,
                              void* d_out, int out_size, void* d_ws, size_t ws_size,
                              hipStream_t stream) {
    const float* x  = (const float*)d_in[0];
    const float* cw = (const float*)d_in[1];   // [F,K]
    const float* sw = (const float*)d_in[2];   // [F,CIN]
    const float* w  = (const float*)d_in[3];   // [F]
    const float* bs = (const float*)d_in[4];   // [F]
    float* out = (float*)d_out;

    hipMemsetAsync(d_out, 0, (size_t)out_size * sizeof(float), stream);

    const size_t bandBytes = (size_t)FF * 3 * 64 * 16;        // 384 KB
    const size_t wnBytes   = (size_t)FF * sizeof(float);
    const size_t swfBytes  = (size_t)(FF / 16) * 2 * 64 * 16; // 16 KB

    if (bandBytes + wnBytes + swfBytes <= ws_size) {
        uint4* bandB = (uint4*)d_ws;
        float* wnf   = (float*)((char*)d_ws + bandBytes);
        uint4* swF   = (uint4*)((char*)d_ws + bandBytes + wnBytes);
        k_band <<<dim3(FF), 64, 0, stream>>>(cw, sw, w, bandB, wnf, swF);
        k_fused<<<dim3(TS / TSEG, BB), 1024, 0, stream>>>(x, swF, bandB, wnf, bs, out);
    } else {
        k_naive<<<dim3(FF, BB), 256, 0, stream>>>(x, cw, sw, w, bs, out);
    }
}

// Round 7
// 129.533 us; speedup vs baseline: 1.1092x; 1.0814x over previous
//
#include <hip/hip_runtime.h>
#include <hip/hip_bf16.h>
#include <cstdint>
#include <cstddef>

#define BB   64
#define CINN 64
#define TS   4096
#define FF   128
#define KS   64
#define TOUT (TS - KS + 1)   // 4033

// ---- fused-kernel tiling ----
#define TSEG 256             // outputs per block (one 256-output banded-MFMA tile, 16x16 D)
#define XROW 320             // t-extent of staged x / computed y (TSEG + KS)
#define SXW  324             // xT row stride in u32 words (mult of 4 -> b128 rows, 2-way banks)
#define YWW  168             // yL row stride in u32 words (336 bf16: 320 y + 16 zero pad)
#define GF   32              // filters per group (4 sequential groups -> yL fits 21.5 KB)

typedef __attribute__((ext_vector_type(8))) short short8;
typedef __attribute__((ext_vector_type(4))) float f32x4;
union FragU { unsigned int u[4]; short8 v; uint4 q4; };

static __device__ __forceinline__ unsigned int f2bf_u(float f) {
    __hip_bfloat16 h = __float2bfloat16(f);
    return (unsigned int)*reinterpret_cast<unsigned short*>(&h);
}

// ---- Setup: banded temporal-B fragments (R5/R6-validated) + sw bf16 fragments +
//      fused norm weights ----
// bandB[(f*3+s)*64 + lane] = 8 bf16: B_s[k=8q+j][n] = cw[32s+k-n] (0 outside [0,64))
// swF[(ft*2+s)*64 + lane]  = 8 bf16: sw[16ft+(l&15)][32s+8q+j]  (B-operand frag, N=filter)
__global__ void k_band(const float* __restrict__ cw, const float* __restrict__ sw,
                       const float* __restrict__ weight,
                       uint4* __restrict__ bandB, float* __restrict__ wnf,
                       uint4* __restrict__ swF) {
    const int f = blockIdx.x, l = threadIdx.x;
    const int n = l & 15, q = l >> 4;
    for (int s = 0; s < 3; ++s) {
        FragU o;
#pragma unroll
        for (int i = 0; i < 4; ++i) {
            int i0 = 32 * s + 8 * q + 2 * i - n;
            int i1 = i0 + 1;
            float a = (i0 >= 0 && i0 < KS) ? cw[(size_t)f * KS + i0] : 0.f;
            float c = (i1 >= 0 && i1 < KS) ? cw[(size_t)f * KS + i1] : 0.f;
            o.u[i] = f2bf_u(a) | (f2bf_u(c) << 16);
        }
        bandB[((size_t)f * 3 + s) * 64 + l] = o.q4;
    }
    // sw bf16 fragments: blocks f = 0,16,32,... build filter-tile ft = f>>4
    if ((f & 15) == 0) {
        const int ft = f >> 4;
        for (int s = 0; s < 2; ++s) {
            FragU o;
#pragma unroll
            for (int i = 0; i < 4; ++i) {
                const float* sr = sw + (size_t)(16 * ft + n) * CINN + 32 * s + 8 * q + 2 * i;
                o.u[i] = f2bf_u(sr[0]) | (f2bf_u(sr[1]) << 16);
            }
            swF[((size_t)ft * 2 + s) * 64 + l] = o.q4;
        }
    }
    // per-filter weight * rsqrt(|sw_f|^2 * |cw_f|^2) * scale / TOUT
    float a = sw[(size_t)f * CINN + l], c = cw[(size_t)f * KS + l];
    float v = a * a, u = c * c;
    for (int off = 32; off > 0; off >>= 1) {
        v += __shfl_down(v, off, 64);
        u += __shfl_down(u, off, 64);
    }
    if (l == 0) wnf[f] = weight[f] * rsqrtf(v * u) * (64.0f / (float)TOUT);
}

// ============ Fused kernel: 512-thread blocks -> 2 INDEPENDENT blocks/CU ============
// R3/R4/R5 A/B/A established: __launch_bounds__ 2nd arg acts as the effective
// waves-per-EU residency cap. (1024,4)=1 block/CU; (1024,8)=2 blocks but strangles
// the allocator (R4 spill). With 512-thread blocks, (512,4) -> 16 waves/CU = 2 blocks
// under BOTH semantics, with a 128-VGPR budget (no squeeze possible).
// Two barrier domains per CU: block B computes through block A's barrier drains and
// global-load waits (the measured idle, since LDS/VALU/MFMA/HBM are all <60%).
// 8 waves: staging 4 ch-pairs/wave; GEMM = 1 tt/wave x BOTH filter-tiles (swF frags
// hoisted per group, halves GEMM LDS reads vs R5); temporal = 4 filters/wave.
__global__ __launch_bounds__(512, 4) void k_fused(
    const float* __restrict__ x, const uint4* __restrict__ swF,
    const uint4* __restrict__ bandB, const float* __restrict__ wnf,
    const float* __restrict__ bias, float* __restrict__ out)
{
    __shared__ unsigned int xT[32 * SXW];   // 41,472 B
    __shared__ unsigned int yL[GF * YWW];   // 21,504 B (first 10,240 B reused as sq partials)
    __shared__ float sqA[XROW];             // 1,280 B
    __shared__ float rinvA[XROW];           // 1,280 B
    __shared__ float wred[8];

    const int tid = threadIdx.x;
    const int w = tid >> 6, l = tid & 63;   // w in 0..7
    const int m = l & 15, q = l >> 4;
    const int b = blockIdx.y;
    const int t0 = blockIdx.x * TSEG;

    // ---------- Phase 1: stage xT (bf16 ch-pairs, [cp][t]) + per-wave sq partials ----------
    {
        const float* xb = x + (size_t)b * CINN * TS;
        float* sqp = (float*)yL;            // [8][XROW] f32 partials
        float4 s4a = {0.f, 0.f, 0.f, 0.f}, s4b = {0.f, 0.f, 0.f, 0.f};
#pragma unroll
        for (int r = 0; r < 4; ++r) {
            const int cp = w + 8 * r;       // channel pair (2cp, 2cp+1)
            const float* x0 = xb + (size_t)(2 * cp) * TS;
            {
                int p = t0 + 4 * l; if (p > TS - 4) p = TS - 4;   // tail clamp (finite dups)
                float4 v0 = *(const float4*)(x0 + p);
                float4 v1 = *(const float4*)(x0 + TS + p);
                s4a.x += v0.x * v0.x + v1.x * v1.x;
                s4a.y += v0.y * v0.y + v1.y * v1.y;
                s4a.z += v0.z * v0.z + v1.z * v1.z;
                s4a.w += v0.w * v0.w + v1.w * v1.w;
                FragU o;
                o.u[0] = f2bf_u(v0.x) | (f2bf_u(v1.x) << 16);
                o.u[1] = f2bf_u(v0.y) | (f2bf_u(v1.y) << 16);
                o.u[2] = f2bf_u(v0.z) | (f2bf_u(v1.z) << 16);
                o.u[3] = f2bf_u(v0.w) | (f2bf_u(v1.w) << 16);
                *(uint4*)&xT[cp * SXW + 4 * l] = o.q4;            // aligned b128, uniform banks
            }
            if (l < 16) {                   // tail t-local 256..319
                int p = t0 + 256 + 4 * l; if (p > TS - 4) p = TS - 4;
                float4 v0 = *(const float4*)(x0 + p);
                float4 v1 = *(const float4*)(x0 + TS + p);
                s4b.x += v0.x * v0.x + v1.x * v1.x;
                s4b.y += v0.y * v0.y + v1.y * v1.y;
                s4b.z += v0.z * v0.z + v1.z * v1.z;
                s4b.w += v0.w * v0.w + v1.w * v1.w;
                FragU o;
                o.u[0] = f2bf_u(v0.x) | (f2bf_u(v1.x) << 16);
                o.u[1] = f2bf_u(v0.y) | (f2bf_u(v1.y) << 16);
                o.u[2] = f2bf_u(v0.z) | (f2bf_u(v1.z) << 16);
                o.u[3] = f2bf_u(v0.w) | (f2bf_u(v1.w) << 16);
                *(uint4*)&xT[cp * SXW + 256 + 4 * l] = o.q4;
            }
        }
        *(float4*)(sqp + w * XROW + 4 * l) = s4a;
        if (l < 16) *(float4*)(sqp + w * XROW + 256 + 4 * l) = s4b;
    }
    __syncthreads();

    // ---------- Phase 2: reduce sq partials into sqA ----------
    if (tid < XROW) {
        const float* sqp = (const float*)yL;
        float s = 0.f;
#pragma unroll
        for (int i = 0; i < 8; ++i) s += sqp[i * XROW + tid];
        sqA[tid] = s;
    }
    __syncthreads();

    // ---------- Phase 3a (wave 7): sliding-window rinv: sqA -> rinvA ----------
    // Runs concurrently with group-0 GEMM; both complete before the group-0 sync.
    // Wave 7 has the lightest GEMM load (2 tt-iters vs 3 for w<4).
    if (w == 7 && l < 32) {
        const int base = 8 * l;
        float s = 0.f, hd[8], tl[8];
#pragma unroll
        for (int k = 0; k < 64; ++k) {
            float v = sqA[base + k];
            if (k < 8) hd[k] = v;
            s += v;
        }
#pragma unroll
        for (int j = 0; j < 8; ++j) tl[j] = sqA[base + 64 + j];
#pragma unroll
        for (int j = 0; j < 8; ++j) {
            int tpos = t0 + base + j;
            rinvA[base + j] = (tpos < TOUT) ? rsqrtf(s) : 0.f;   // masks tail outputs
            s += tl[j] - hd[j];
        }
    }

    // ---------- main loop: 4 filter-groups of 32 ----------
    float acc = 0.f;
    for (int g = 0; g < 4; ++g) {
        // ---- GEMM (swapped operands): each wave owns a tt, computes BOTH filter-tiles ----
        {
            FragU s0[2], s1[2];             // group's sw frags, tt-invariant (16 VGPR)
#pragma unroll
            for (int ftl = 0; ftl < 2; ++ftl) {
                const int ft = 2 * g + ftl;
                s0[ftl].q4 = swF[((size_t)ft * 2 + 0) * 64 + l];
                s1[ftl].q4 = swF[((size_t)ft * 2 + 1) * 64 + l];
            }
            for (int tt = w; tt < 20; tt += 8) {
                FragU b0, b1;               // x frags: strided b32 reads (2-way banks, free)
#pragma unroll
                for (int i = 0; i < 4; ++i) {
                    b0.u[i] = xT[(4 * q + i) * SXW + 16 * tt + m];
                    b1.u[i] = xT[(16 + 4 * q + i) * SXW + 16 * tt + m];
                }
#pragma unroll
                for (int ftl = 0; ftl < 2; ++ftl) {
                    f32x4 d = {0.f, 0.f, 0.f, 0.f};
                    d = __builtin_amdgcn_mfma_f32_16x16x32_bf16(b0.v, s0[ftl].v, d, 0, 0, 0);
                    d = __builtin_amdgcn_mfma_f32_16x16x32_bf16(b1.v, s1[ftl].v, d, 0, 0, 0);
                    const int fl = 16 * ftl + m;                 // group-local filter row
                    uint2 o;
                    o.x = f2bf_u(d[0]) | (f2bf_u(d[1]) << 16);   // t = 16tt+4q, +1
                    o.y = f2bf_u(d[2]) | (f2bf_u(d[3]) << 16);   // t = 16tt+4q+2, +3
                    *(uint2*)(yL + fl * YWW + 8 * tt + 2 * q) = o;
                }
            }
            // zero finite-pad words 160..167 of each row once; GEMM never writes >=160,
            // so the pads stay zero for all later groups.
            if (g == 0 && tid < 256) yL[(tid >> 3) * YWW + 160 + (tid & 7)] = 0u;
        }
        __syncthreads();

        // ---- banded temporal MFMA: wave w consumes group-local filters 4w..4w+3 ----
        {
            float rr[4];
#pragma unroll
            for (int r = 0; r < 4; ++r) rr[r] = rinvA[64 * q + 16 * r + m];   // broadcast reads
#pragma unroll 2
            for (int j = 0; j < 4; ++j) {
                const int fl = 4 * w + j;                    // 0..31
                const int f  = GF * g + fl;
                const uint4* bb = bandB + (size_t)f * 3 * 64;
                FragU B0, B1, B2;
                B0.q4 = bb[l]; B1.q4 = bb[64 + l]; B2.q4 = bb[128 + l];
                const int abase = fl * YWW + 8 * m + 4 * q;  // 16B-aligned word index
                FragU a0, a1, a2;
                a0.q4 = *(const uint4*)(yL + abase);
                a1.q4 = *(const uint4*)(yL + abase + 16);
                a2.q4 = *(const uint4*)(yL + abase + 32);
                f32x4 d = {0.f, 0.f, 0.f, 0.f};
                d = __builtin_amdgcn_mfma_f32_16x16x32_bf16(a0.v, B0.v, d, 0, 0, 0);
                d = __builtin_amdgcn_mfma_f32_16x16x32_bf16(a1.v, B1.v, d, 0, 0, 0);
                d = __builtin_amdgcn_mfma_f32_16x16x32_bf16(a2.v, B2.v, d, 0, 0, 0);
                float facc = 0.f;
#pragma unroll
                for (int r = 0; r < 4; ++r) facc += fabsf(d[r]) * rr[r];
                acc += wnf[f] * facc;
            }
        }
        __syncthreads();                    // yL reusable for next group's GEMM
    }

    // ---------- block reduction + atomic ----------
    for (int off = 32; off > 0; off >>= 1) acc += __shfl_down(acc, off, 64);
    if (l == 0) wred[w] = acc;
    __syncthreads();
    if (tid == 0) {
        float s = 0.f;
#pragma unroll
        for (int i = 0; i < 8; ++i) s += wred[i];
        atomicAdd(out + b, s);
    }
    if (blockIdx.x == 0 && tid < FF) {
        float v = bias[tid];
        for (int off = 32; off > 0; off >>= 1) v += __shfl_down(v, off, 64);
        if ((tid & 63) == 0) atomicAdd(out + b, v);
    }
}

// --------- Fallback (no workspace): one block per (f,b), LDS rows ----------
__global__ __launch_bounds__(256) void k_naive(
    const float* __restrict__ x, const float* __restrict__ cw,
    const float* __restrict__ sw, const float* __restrict__ weight,
    const float* __restrict__ bias, float* __restrict__ out)
{
    __shared__ float yl[TS];
    __shared__ float ql[TS];
    __shared__ float wred[4];
    const int f = blockIdx.x, b = blockIdx.y, tid = threadIdx.x;
    for (int t = tid; t < TS; t += 256) {
        float a = 0.f, s = 0.f;
        for (int c = 0; c < CINN; ++c) {
            float v = x[((size_t)b * CINN + c) * TS + t];
            a += sw[(size_t)f * CINN + c] * v;
            s += v * v;
        }
        yl[t] = a; ql[t] = s;
    }
    __syncthreads();
    float acc = 0.f;
    for (int t = tid; t < TOUT; t += 256) {
        float cv = 0.f, sl = 0.f;
        for (int k = 0; k < KS; ++k) { cv += cw[(size_t)f * KS + k] * yl[t + k]; sl += ql[t + k]; }
        acc += fabsf(cv) * rsqrtf(sl);
    }
    float ssw = 0.f, scw = 0.f;
    for (int c = 0; c < CINN; ++c) { float v = sw[(size_t)f * CINN + c]; ssw += v * v; }
    for (int k = 0; k < KS; ++k)   { float v = cw[(size_t)f * KS + k];  scw += v * v; }
    const float wnf = weight[f] * rsqrtf(ssw * scw) * 64.0f / (float)TOUT;
    for (int off = 32; off > 0; off >>= 1) acc += __shfl_down(acc, off, 64);
    if ((tid & 63) == 0) wred[tid >> 6] = acc;
    __syncthreads();
    if (tid == 0) {
        float tot = (wred[0] + wred[1] + wred[2] + wred[3]) * wnf;
        if (f == 0) {
            float bsum = 0.f;
            for (int ff = 0; ff < FF; ++ff) bsum += bias[ff];
            tot += bsum;
        }
        atomicAdd(out + b, tot);
    }
}

extern "C" void kernel_launch(void* const* d_in, const int* in_sizes, int n_in,
                              void* d_out, int out_size, void* d_ws, size_t ws_size,
                              hipStream_t stream) {
    const float* x  = (const float*)d_in[0];
    const float* cw = (const float*)d_in[1];   // [F,K]
    const float* sw = (const float*)d_in[2];   // [F,CIN]
    const float* w  = (const float*)d_in[3];   // [F]
    const float* bs = (const float*)d_in[4];   // [F]
    float* out = (float*)d_out;

    hipMemsetAsync(d_out, 0, (size_t)out_size * sizeof(float), stream);

    const size_t bandBytes = (size_t)FF * 3 * 64 * 16;        // 384 KB
    const size_t wnBytes   = (size_t)FF * sizeof(float);
    const size_t swfBytes  = (size_t)(FF / 16) * 2 * 64 * 16; // 16 KB

    if (bandBytes + wnBytes + swfBytes <= ws_size) {
        uint4* bandB = (uint4*)d_ws;
        float* wnf   = (float*)((char*)d_ws + bandBytes);
        uint4* swF   = (uint4*)((char*)d_ws + bandBytes + wnBytes);
        k_band <<<dim3(FF), 64, 0, stream>>>(cw, sw, w, bandB, wnf, swF);
        k_fused<<<dim3(TS / TSEG, BB), 512, 0, stream>>>(x, swF, bandB, wnf, bs, out);
    } else {
        k_naive<<<dim3(FF, BB), 256, 0, stream>>>(x, cw, sw, w, bs, out);
    }
}

// Round 8
// 127.544 us; speedup vs baseline: 1.1265x; 1.0156x over previous
//
#include <hip/hip_runtime.h>
#include <hip/hip_bf16.h>
#include <cstdint>
#include <cstddef>

#define BB   64
#define CINN 64
#define TS   4096
#define FF   128
#define KS   64
#define TOUT (TS - KS + 1)   // 4033

// ---- fused-kernel tiling ----
#define TSEG 256             // outputs per block (one 256-output banded-MFMA tile, 16x16 D)
#define XROW 320             // t-extent of staged x / computed y (TSEG + KS)
#define SXW  324             // xT row stride in u32 words (mult of 4 -> b128 rows, 2-way banks)
#define YWW  168             // yL row stride in u32 words (336 bf16: 320 y + 16 zero pad)
#define GF   16              // filters per group: 8 groups, DOUBLE-BUFFERED yL (2x10.5 KB)
#define YBUF (GF * YWW)      // 2688 words per buffer

typedef __attribute__((ext_vector_type(8))) short short8;
typedef __attribute__((ext_vector_type(4))) float f32x4;
union FragU { unsigned int u[4]; short8 v; uint4 q4; };

static __device__ __forceinline__ unsigned int f2bf_u(float f) {
    __hip_bfloat16 h = __float2bfloat16(f);
    return (unsigned int)*reinterpret_cast<unsigned short*>(&h);
}

// ---- Setup: banded temporal-B fragments (R5/R6-validated) + sw bf16 fragments +
//      fused norm weights ----
// bandB[(f*3+s)*64 + lane] = 8 bf16: B_s[k=8q+j][n] = cw[32s+k-n] (0 outside [0,64))
// swF[(ft*2+s)*64 + lane]  = 8 bf16: sw[16ft+(l&15)][32s+8q+j]  (B-operand frag, N=filter)
__global__ void k_band(const float* __restrict__ cw, const float* __restrict__ sw,
                       const float* __restrict__ weight,
                       uint4* __restrict__ bandB, float* __restrict__ wnf,
                       uint4* __restrict__ swF) {
    const int f = blockIdx.x, l = threadIdx.x;
    const int n = l & 15, q = l >> 4;
    for (int s = 0; s < 3; ++s) {
        FragU o;
#pragma unroll
        for (int i = 0; i < 4; ++i) {
            int i0 = 32 * s + 8 * q + 2 * i - n;
            int i1 = i0 + 1;
            float a = (i0 >= 0 && i0 < KS) ? cw[(size_t)f * KS + i0] : 0.f;
            float c = (i1 >= 0 && i1 < KS) ? cw[(size_t)f * KS + i1] : 0.f;
            o.u[i] = f2bf_u(a) | (f2bf_u(c) << 16);
        }
        bandB[((size_t)f * 3 + s) * 64 + l] = o.q4;
    }
    // sw bf16 fragments: blocks f = 0,16,32,... build filter-tile ft = f>>4
    if ((f & 15) == 0) {
        const int ft = f >> 4;
        for (int s = 0; s < 2; ++s) {
            FragU o;
#pragma unroll
            for (int i = 0; i < 4; ++i) {
                const float* sr = sw + (size_t)(16 * ft + n) * CINN + 32 * s + 8 * q + 2 * i;
                o.u[i] = f2bf_u(sr[0]) | (f2bf_u(sr[1]) << 16);
            }
            swF[((size_t)ft * 2 + s) * 64 + l] = o.q4;
        }
    }
    // per-filter weight * rsqrt(|sw_f|^2 * |cw_f|^2) * scale / TOUT
    float a = sw[(size_t)f * CINN + l], c = cw[(size_t)f * KS + l];
    float v = a * a, u = c * c;
    for (int off = 32; off > 0; off >>= 1) {
        v += __shfl_down(v, off, 64);
        u += __shfl_down(u, off, 64);
    }
    if (l == 0) wnf[f] = weight[f] * rsqrtf(v * u) * (64.0f / (float)TOUT);
}

// ============ Fused kernel: double-buffered yL, GEMM(g+1) || temporal(g) ============
// 512-thread blocks, 2 blocks/CU (R7-proven). NEW vs R7: groups of 16 filters with
// TWO yL buffers; each barrier interval contains next group's GEMM (MFMA + ds_write)
// AND current group's temporal (bandB L2 loads + yL ds_read_b128 + MFMA), so the
// temporal phase's L2/LDS latency hides under GEMM work instead of draining at a
// dedicated barrier. One barrier per group (buffers disjoint within an interval).
__global__ __launch_bounds__(512, 4) void k_fused(
    const float* __restrict__ x, const uint4* __restrict__ swF,
    const uint4* __restrict__ bandB, const float* __restrict__ wnf,
    const float* __restrict__ bias, float* __restrict__ out)
{
    __shared__ unsigned int xT[32 * SXW];   // 41,472 B
    __shared__ unsigned int yL[2 * YBUF];   // 21,504 B (first 10,240 B reused as sq partials)
    __shared__ float sqA[XROW];             // 1,280 B
    __shared__ float rinvA[XROW];           // 1,280 B
    __shared__ float wred[8];

    const int tid = threadIdx.x;
    const int w = tid >> 6, l = tid & 63;   // w in 0..7
    const int m = l & 15, q = l >> 4;
    const int b = blockIdx.y;
    const int t0 = blockIdx.x * TSEG;

    // ---------- Phase 1: stage xT (bf16 ch-pairs, [cp][t]) + per-wave sq partials ----------
    {
        const float* xb = x + (size_t)b * CINN * TS;
        float* sqp = (float*)yL;            // [8][XROW] f32 partials
        float4 s4a = {0.f, 0.f, 0.f, 0.f}, s4b = {0.f, 0.f, 0.f, 0.f};
#pragma unroll
        for (int r = 0; r < 4; ++r) {
            const int cp = w + 8 * r;       // channel pair (2cp, 2cp+1)
            const float* x0 = xb + (size_t)(2 * cp) * TS;
            {
                int p = t0 + 4 * l; if (p > TS - 4) p = TS - 4;   // tail clamp (finite dups)
                float4 v0 = *(const float4*)(x0 + p);
                float4 v1 = *(const float4*)(x0 + TS + p);
                s4a.x += v0.x * v0.x + v1.x * v1.x;
                s4a.y += v0.y * v0.y + v1.y * v1.y;
                s4a.z += v0.z * v0.z + v1.z * v1.z;
                s4a.w += v0.w * v0.w + v1.w * v1.w;
                FragU o;
                o.u[0] = f2bf_u(v0.x) | (f2bf_u(v1.x) << 16);
                o.u[1] = f2bf_u(v0.y) | (f2bf_u(v1.y) << 16);
                o.u[2] = f2bf_u(v0.z) | (f2bf_u(v1.z) << 16);
                o.u[3] = f2bf_u(v0.w) | (f2bf_u(v1.w) << 16);
                *(uint4*)&xT[cp * SXW + 4 * l] = o.q4;            // aligned b128, uniform banks
            }
            if (l < 16) {                   // tail t-local 256..319
                int p = t0 + 256 + 4 * l; if (p > TS - 4) p = TS - 4;
                float4 v0 = *(const float4*)(x0 + p);
                float4 v1 = *(const float4*)(x0 + TS + p);
                s4b.x += v0.x * v0.x + v1.x * v1.x;
                s4b.y += v0.y * v0.y + v1.y * v1.y;
                s4b.z += v0.z * v0.z + v1.z * v1.z;
                s4b.w += v0.w * v0.w + v1.w * v1.w;
                FragU o;
                o.u[0] = f2bf_u(v0.x) | (f2bf_u(v1.x) << 16);
                o.u[1] = f2bf_u(v0.y) | (f2bf_u(v1.y) << 16);
                o.u[2] = f2bf_u(v0.z) | (f2bf_u(v1.z) << 16);
                o.u[3] = f2bf_u(v0.w) | (f2bf_u(v1.w) << 16);
                *(uint4*)&xT[cp * SXW + 256 + 4 * l] = o.q4;
            }
        }
        *(float4*)(sqp + w * XROW + 4 * l) = s4a;
        if (l < 16) *(float4*)(sqp + w * XROW + 256 + 4 * l) = s4b;
    }
    __syncthreads();

    // ---------- Phase 2: reduce sq partials into sqA ----------
    if (tid < XROW) {
        const float* sqp = (const float*)yL;
        float s = 0.f;
#pragma unroll
        for (int i = 0; i < 8; ++i) s += sqp[i * XROW + tid];
        sqA[tid] = s;
    }
    __syncthreads();

    // ---- GEMM for one filter-tile (ft = group index, GF=16) into buffer yb ----
    auto GEMM = [&](int ft, unsigned int* yb) {
        FragU s0, s1;                       // transient sw frags straight from L2
        s0.q4 = swF[((size_t)ft * 2 + 0) * 64 + l];
        s1.q4 = swF[((size_t)ft * 2 + 1) * 64 + l];
        for (int tt = w; tt < 20; tt += 8) {
            FragU b0, b1;                   // x frags: strided b32 reads (2-way banks, free)
#pragma unroll
            for (int i = 0; i < 4; ++i) {
                b0.u[i] = xT[(4 * q + i) * SXW + 16 * tt + m];
                b1.u[i] = xT[(16 + 4 * q + i) * SXW + 16 * tt + m];
            }
            f32x4 d = {0.f, 0.f, 0.f, 0.f};
            d = __builtin_amdgcn_mfma_f32_16x16x32_bf16(b0.v, s0.v, d, 0, 0, 0);
            d = __builtin_amdgcn_mfma_f32_16x16x32_bf16(b1.v, s1.v, d, 0, 0, 0);
            uint2 o;
            o.x = f2bf_u(d[0]) | (f2bf_u(d[1]) << 16);   // t = 16tt+4q, +1
            o.y = f2bf_u(d[2]) | (f2bf_u(d[3]) << 16);   // t = 16tt+4q+2, +3
            *(uint2*)(yb + m * YWW + 8 * tt + 2 * q) = o;
        }
    };

    // ---------- Prologue interval: wave-7 rinv || GEMM(0) || pad zeroing ----------
    if (w == 7 && l < 32) {
        const int base = 8 * l;
        float s = 0.f, hd[8], tl[8];
#pragma unroll
        for (int k = 0; k < 64; ++k) {
            float v = sqA[base + k];
            if (k < 8) hd[k] = v;
            s += v;
        }
#pragma unroll
        for (int j = 0; j < 8; ++j) tl[j] = sqA[base + 64 + j];
#pragma unroll
        for (int j = 0; j < 8; ++j) {
            int tpos = t0 + base + j;
            rinvA[base + j] = (tpos < TOUT) ? rsqrtf(s) : 0.f;   // masks tail outputs
            s += tl[j] - hd[j];
        }
    }
    GEMM(0, yL);
    // zero finite-pad words 160..167 of every row in BOTH buffers, once.
    // (GEMM never writes words >=160, so pads stay zero for all groups.)
    if (tid < 256) yL[(tid >> 7) * YBUF + ((tid >> 3) & 15) * YWW + 160 + (tid & 7)] = 0u;
    __syncthreads();

    // rinv for this lane's 4 output rows, register-resident for the whole loop
    float rr[4];
#pragma unroll
    for (int r = 0; r < 4; ++r) rr[r] = rinvA[64 * q + 16 * r + m];   // broadcast reads

    // ---------- main loop: 8 groups of 16; GEMM(g+1) || temporal(g), 1 barrier/group ----------
    float acc = 0.f;
    for (int g = 0; g < 8; ++g) {
        if (g < 7) GEMM(g + 1, yL + ((g + 1) & 1) * YBUF);
        // temporal(g) from buf[g&1]: wave w consumes filters f = 16g + 2w + j
        const unsigned int* yb = yL + (g & 1) * YBUF;
#pragma unroll
        for (int j = 0; j < 2; ++j) {
            const int fl = 2 * w + j;                    // 0..15
            const int f  = GF * g + fl;
            const uint4* bb = bandB + (size_t)f * 3 * 64;
            FragU B0, B1, B2;
            B0.q4 = bb[l]; B1.q4 = bb[64 + l]; B2.q4 = bb[128 + l];
            const int abase = fl * YWW + 8 * m + 4 * q;  // 16B-aligned word index
            FragU a0, a1, a2;
            a0.q4 = *(const uint4*)(yb + abase);
            a1.q4 = *(const uint4*)(yb + abase + 16);
            a2.q4 = *(const uint4*)(yb + abase + 32);
            f32x4 d = {0.f, 0.f, 0.f, 0.f};
            d = __builtin_amdgcn_mfma_f32_16x16x32_bf16(a0.v, B0.v, d, 0, 0, 0);
            d = __builtin_amdgcn_mfma_f32_16x16x32_bf16(a1.v, B1.v, d, 0, 0, 0);
            d = __builtin_amdgcn_mfma_f32_16x16x32_bf16(a2.v, B2.v, d, 0, 0, 0);
            float facc = 0.f;
#pragma unroll
            for (int r = 0; r < 4; ++r) facc += fabsf(d[r]) * rr[r];
            acc += wnf[f] * facc;
        }
        __syncthreads();    // temporal(g) reads done before GEMM(g+2) overwrites buf[g&1];
                            // GEMM(g+1) writes done before temporal(g+1) reads buf[(g+1)&1]
    }

    // ---------- block reduction + atomic ----------
    for (int off = 32; off > 0; off >>= 1) acc += __shfl_down(acc, off, 64);
    if (l == 0) wred[w] = acc;
    __syncthreads();
    if (tid == 0) {
        float s = 0.f;
#pragma unroll
        for (int i = 0; i < 8; ++i) s += wred[i];
        atomicAdd(out + b, s);
    }
    if (blockIdx.x == 0 && tid < FF) {
        float v = bias[tid];
        for (int off = 32; off > 0; off >>= 1) v += __shfl_down(v, off, 64);
        if ((tid & 63) == 0) atomicAdd(out + b, v);
    }
}

// --------- Fallback (no workspace): one block per (f,b), LDS rows ----------
__global__ __launch_bounds__(256) void k_naive(
    const float* __restrict__ x, const float* __restrict__ cw,
    const float* __restrict__ sw, const float* __restrict__ weight,
    const float* __restrict__ bias, float* __restrict__ out)
{
    __shared__ float yl[TS];
    __shared__ float ql[TS];
    __shared__ float wred[4];
    const int f = blockIdx.x, b = blockIdx.y, tid = threadIdx.x;
    for (int t = tid; t < TS; t += 256) {
        float a = 0.f, s = 0.f;
        for (int c = 0; c < CINN; ++c) {
            float v = x[((size_t)b * CINN + c) * TS + t];
            a += sw[(size_t)f * CINN + c] * v;
            s += v * v;
        }
        yl[t] = a; ql[t] = s;
    }
    __syncthreads();
    float acc = 0.f;
    for (int t = tid; t < TOUT; t += 256) {
        float cv = 0.f, sl = 0.f;
        for (int k = 0; k < KS; ++k) { cv += cw[(size_t)f * KS + k] * yl[t + k]; sl += ql[t + k]; }
        acc += fabsf(cv) * rsqrtf(sl);
    }
    float ssw = 0.f, scw = 0.f;
    for (int c = 0; c < CINN; ++c) { float v = sw[(size_t)f * CINN + c]; ssw += v * v; }
    for (int k = 0; k < KS; ++k)   { float v = cw[(size_t)f * KS + k];  scw += v * v; }
    const float wnf = weight[f] * rsqrtf(ssw * scw) * 64.0f / (float)TOUT;
    for (int off = 32; off > 0; off >>= 1) acc += __shfl_down(acc, off, 64);
    if ((tid & 63) == 0) wred[tid >> 6] = acc;
    __syncthreads();
    if (tid == 0) {
        float tot = (wred[0] + wred[1] + wred[2] + wred[3]) * wnf;
        if (f == 0) {
            float bsum = 0.f;
            for (int ff = 0; ff < FF; ++ff) bsum += bias[ff];
            tot += bsum;
        }
        atomicAdd(out + b, tot);
    }
}

extern "C" void kernel_launch(void* const* d_in, const int* in_sizes, int n_in,
                              void* d_out, int out_size, void* d_ws, size_t ws_size,
                              hipStream_t stream) {
    const float* x  = (const float*)d_in[0];
    const float* cw = (const float*)d_in[1];   // [F,K]
    const float* sw = (const float*)d_in[2];   // [F,CIN]
    const float* w  = (const float*)d_in[3];   // [F]
    const float* bs = (const float*)d_in[4];   // [F]
    float* out = (float*)d_out;

    hipMemsetAsync(d_out, 0, (size_t)out_size * sizeof(float), stream);

    const size_t bandBytes = (size_t)FF * 3 * 64 * 16;        // 384 KB
    const size_t wnBytes   = (size_t)FF * sizeof(float);
    const size_t swfBytes  = (size_t)(FF / 16) * 2 * 64 * 16; // 16 KB

    if (bandBytes + wnBytes + swfBytes <= ws_size) {
        uint4* bandB = (uint4*)d_ws;
        float* wnf   = (float*)((char*)d_ws + bandBytes);
        uint4* swF   = (uint4*)((char*)d_ws + bandBytes + wnBytes);
        k_band <<<dim3(FF), 64, 0, stream>>>(cw, sw, w, bandB, wnf, swF);
        k_fused<<<dim3(TS / TSEG, BB), 512, 0, stream>>>(x, swF, bandB, wnf, bs, out);
    } else {
        k_naive<<<dim3(FF, BB), 256, 0, stream>>>(x, cw, sw, w, bs, out);
    }
}